// Round 3
// baseline (380.323 us; speedup 1.0000x reference)
//
#include <hip/hip_runtime.h>
#include <hip/hip_bf16.h>

#define BIGV 1.0e9f

static constexpr int B_ = 32;
static constexpr int L_ = 1024;
static constexpr int F_ = 128;
static constexpr int S_ = 4;               // lane stagger (skew factor)
static constexpr int SKEW_U = 1292;        // skewed rows; max u accessed = 1287
static constexpr size_t SKEW_PB = (size_t)SKEW_U * 1024;  // floats per batch
static constexpr size_t OFF_N1 = (size_t)B_ * SKEW_PB;
static constexpr size_t OFF_N2 = OFF_N1 + (size_t)B_ * L_;
static constexpr size_t OFF_CNT = OFF_N2 + (size_t)B_ * L_;  // 256 int counters
static constexpr int PF_ = 8;
static constexpr int TSTEPS_ = 1280;       // 1024 + 4*63 = 1276, padded to x8

typedef __attribute__((ext_vector_type(8))) short short8;
typedef __attribute__((ext_vector_type(4))) float f32x4;

__device__ __forceinline__ unsigned pack2(float x, float y) {
  union { float f; unsigned u; } a, b;
  a.f = x; b.f = y;
  unsigned lo = (a.u + 0x7FFFu + ((a.u >> 16) & 1u)) >> 16;
  unsigned hi = (b.u + 0x7FFFu + ((b.u >> 16) & 1u)) >> 16;
  return lo | (hi << 16);
}

// one wave per row of 128 floats; also zeroes the progress counters (block 0)
__global__ void norm_kernel(const float* __restrict__ s1, const float* __restrict__ s2,
                            float* __restrict__ ws) {
  if (blockIdx.x == 0) ((int*)(ws + OFF_CNT))[threadIdx.x] = 0;
  int gt   = blockIdx.x * blockDim.x + threadIdx.x;
  int wid  = gt >> 6;
  int lane = gt & 63;
  const float* src = (wid < B_ * L_) ? (s1 + (size_t)wid * F_)
                                     : (s2 + (size_t)(wid - B_ * L_) * F_);
  float2 v = ((const float2*)src)[lane];
  float s = v.x * v.x + v.y * v.y;
#pragma unroll
  for (int o = 32; o > 0; o >>= 1) s += __shfl_xor(s, o, 64);
  if (lane == 0) ws[OFF_N1 + wid] = s;
}

// blockIdx 0..31: DTW consumers (one wave per batch).
// blockIdx 32..2079: cost producers, tc-major so all batches progress together.
__global__ __launch_bounds__(256, 2) void fused_kernel(const float* __restrict__ s1,
                                                       const float* __restrict__ s2,
                                                       float* __restrict__ ws,
                                                       float* __restrict__ out) {
  __shared__ short aL[128][136];
  __shared__ short bL[128][136];
  __shared__ float q1[128], q2[128];
  int* cnt = (int*)(ws + OFF_CNT);

  if (blockIdx.x >= 32) {
    // ---------------- producer: one 128x128 cost tile ----------------
    const int pid = (int)blockIdx.x - 32;
    const int tc  = pid >> 8;          // column tile (s2 rows)
    const int b   = (pid >> 3) & 31;
    const int tr  = pid & 7;           // row tile (s1 rows)
    const int tid = threadIdx.x;

    const float* Ap = s1 + (size_t)b * L_ * F_ + (size_t)tr * 128 * F_;
    const float* Bp = s2 + (size_t)b * L_ * F_ + (size_t)tc * 128 * F_;

#pragma unroll 4
    for (int it = 0; it < 16; ++it) {
      int idx = it * 1024 + tid * 4;
      int r = idx >> 7, cc = idx & 127;
      float4 va = *(const float4*)(Ap + idx);
      float4 vb = *(const float4*)(Bp + idx);
      *(uint2*)&aL[r][cc] = make_uint2(pack2(va.x, va.y), pack2(va.z, va.w));
      *(uint2*)&bL[r][cc] = make_uint2(pack2(vb.x, vb.y), pack2(vb.z, vb.w));
    }
    if (tid < 128) q1[tid] = ws[OFF_N1 + (size_t)b * L_ + tr * 128 + tid];
    else           q2[tid - 128] = ws[OFF_N2 + (size_t)b * L_ + tc * 128 + (tid - 128)];
    __syncthreads();

    const int wave = tid >> 6, lane = tid & 63, quad = lane >> 4, l16 = lane & 15;
    const int m0 = (wave >> 1) * 64, n0 = (wave & 1) * 64;

    f32x4 acc[4][4] = {};
#pragma unroll
    for (int kc = 0; kc < 4; ++kc) {
      short8 af[4], bf[4];
#pragma unroll
      for (int mi = 0; mi < 4; ++mi)
        af[mi] = *(const short8*)&aL[m0 + mi * 16 + l16][kc * 32 + quad * 8];
#pragma unroll
      for (int nj = 0; nj < 4; ++nj)
        bf[nj] = *(const short8*)&bL[n0 + nj * 16 + l16][kc * 32 + quad * 8];
#pragma unroll
      for (int mi = 0; mi < 4; ++mi)
#pragma unroll
        for (int nj = 0; nj < 4; ++nj)
          acc[mi][nj] = __builtin_amdgcn_mfma_f32_16x16x32_bf16(af[mi], bf[nj], acc[mi][nj], 0, 0, 0);
    }

    float* Cb = ws + (size_t)b * SKEW_PB;
#pragma unroll
    for (int mi = 0; mi < 4; ++mi)
#pragma unroll
      for (int nj = 0; nj < 4; ++nj) {
        int lr0 = m0 + mi * 16 + quad * 4;
        int lc  = n0 + nj * 16 + l16;
        int r0  = tr * 128 + lr0;
        int c   = tc * 128 + lc;
        float4 v;
        v.x = sqrtf(fmaxf(q1[lr0 + 0] + q2[lc] - 2.0f * acc[mi][nj][0], 0.0f));
        v.y = sqrtf(fmaxf(q1[lr0 + 1] + q2[lc] - 2.0f * acc[mi][nj][1], 0.0f));
        v.z = sqrtf(fmaxf(q1[lr0 + 2] + q2[lc] - 2.0f * acc[mi][nj][2], 0.0f));
        v.w = sqrtf(fmaxf(q1[lr0 + 3] + q2[lc] - 2.0f * acc[mi][nj][3], 0.0f));
        *(float4*)&Cb[(size_t)(c + S_ * (r0 >> 4)) * 1024 + r0] = v;
      }
    __syncthreads();                        // all waves' stores complete (to L2)
    if (tid == 0) {
      __threadfence();                      // agent fence: push L2 to coherent point
      atomicAdd(&cnt[b * 8 + tc], 1);       // device-scope progress
    }
    return;
  }

  // ---------------- consumer: DTW for batch b, single wave ----------------
  const int b = blockIdx.x;
  if (threadIdx.x >= 64) return;
  const int lane = threadIdx.x;
  const bool l0 = (lane == 0);
  const float* Cb = ws + (size_t)b * SKEW_PB + lane * 16;

  auto gate = [&](int k) {
    const int* cp = &cnt[b * 8 + k];
    while (__hip_atomic_load(cp, __ATOMIC_ACQUIRE, __HIP_MEMORY_SCOPE_AGENT) < 8)
      __builtin_amdgcn_s_sleep(8);
  };

  gate(0);
  float4 buf[PF_][4];
#pragma unroll
  for (int s = 0; s < PF_; ++s)
#pragma unroll
    for (int k = 0; k < 4; ++k)
      buf[s][k] = *(const float4*)(Cb + (size_t)s * 1024 + k * 4);
  const float* pc = Cb + (size_t)PF_ * 1024;

  float left[16];
#pragma unroll
  for (int r = 0; r < 16; ++r) left[r] = BIGV;
  float bot = BIGV;
  float sh[4] = {BIGV, BIGV, BIGV, BIGV};
  int tm = -S_ * lane;
  float result = 0.0f;

#pragma unroll 8
  for (int t = 0; t < TSTEPS_; ++t) {
    if ((t & 127) == 120 && t < 1016) gate((t + PF_) >> 7);

    float shN = __shfl_up(bot, 1, 64);  // lane-1 bot as of entry of step t

    float4 nb0 = *(const float4*)(pc + 0);
    float4 nb1 = *(const float4*)(pc + 4);
    float4 nb2 = *(const float4*)(pc + 8);
    float4 nb3 = *(const float4*)(pc + 12);
    pc += 1024;

    const float4* cb = buf[t & (PF_ - 1)];
    float cv[16] = { cb[0].x, cb[0].y, cb[0].z, cb[0].w,
                     cb[1].x, cb[1].y, cb[1].z, cb[1].w,
                     cb[2].x, cb[2].y, cb[2].z, cb[2].w,
                     cb[3].x, cb[3].y, cb[3].z, cb[3].w };

    // ring: slot written at step t is read as diag at t+4, as up at t+3
    float dgT = l0 ? ((t == 0) ? 0.0f : BIGV) : sh[t & 3];
    float upT = l0 ? BIGV : sh[(t + 1) & 3];
    bool act = ((unsigned)tm < 1024u);
    float c0 = act ? cv[0] : BIGV;      // off-chain masking; induction keeps
                                        // inactive-lane state >= ~1e9
    float cur = c0 + fminf(fminf(dgT, upT), left[0]);
    float nl[16];
    nl[0] = cur;
#pragma unroll
    for (int r = 1; r < 16; ++r) {
      cur = cv[r] + fminf(fminf(left[r - 1], left[r]), cur);  // v_min3 + v_add
      nl[r] = cur;
    }
#pragma unroll
    for (int r = 0; r < 16; ++r) left[r] = nl[r];
    bot = nl[15];
    sh[t & 3] = shN;

    buf[t & (PF_ - 1)][0] = nb0;
    buf[t & (PF_ - 1)][1] = nb1;
    buf[t & (PF_ - 1)][2] = nb2;
    buf[t & (PF_ - 1)][3] = nb3;

    if (t == 1275) result = bot;  // lane 63 at c=1023: D[1024][1024]
    tm += 1;
  }
  if (lane == 63) out[b] = 1.0f / (1.0f + result * (1.0f / 2048.0f));
}

extern "C" void kernel_launch(void* const* d_in, const int* in_sizes, int n_in,
                              void* d_out, int out_size, void* d_ws, size_t ws_size,
                              hipStream_t stream) {
  const float* s1 = (const float*)d_in[0];
  const float* s2 = (const float*)d_in[1];
  float* out = (float*)d_out;
  float* ws  = (float*)d_ws;

  norm_kernel<<<dim3((2 * B_ * L_) / 4), 256, 0, stream>>>(s1, s2, ws);
  fused_kernel<<<dim3(32 + 2048), 256, 0, stream>>>(s1, s2, ws, out);
}

// Round 4
// 262.847 us; speedup vs baseline: 1.4469x; 1.4469x over previous
//
#include <hip/hip_runtime.h>
#include <hip/hip_bf16.h>

#define BIGV 1.0e9f

static constexpr int B_ = 32;
static constexpr int L_ = 1024;
static constexpr int F_ = 128;
static constexpr int S_ = 4;               // lane stagger (skew factor)
static constexpr int SKEW_U = 1296;        // skewed rows; producer writes <=1275, loader reads <=1279
static constexpr size_t SKEW_PB = (size_t)SKEW_U * 1024;  // floats per batch
static constexpr size_t OFF_N1 = (size_t)B_ * SKEW_PB;
static constexpr size_t OFF_N2 = OFF_N1 + (size_t)B_ * L_;
static constexpr int NSEG_ = 80;           // 80 segments x 16 steps = 1280 >= 1276

typedef __attribute__((ext_vector_type(8))) short short8;
typedef __attribute__((ext_vector_type(4))) float f32x4;

__device__ __forceinline__ unsigned pack2(float x, float y) {
  union { float f; unsigned u; } a, b;
  a.f = x; b.f = y;
  unsigned lo = (a.u + 0x7FFFu + ((a.u >> 16) & 1u)) >> 16;
  unsigned hi = (b.u + 0x7FFFu + ((b.u >> 16) & 1u)) >> 16;
  return lo | (hi << 16);
}

// one wave per row of 128 floats; ws[OFF_N1 + wid] = sum of squares
__global__ void norm_kernel(const float* __restrict__ s1, const float* __restrict__ s2,
                            float* __restrict__ ws) {
  int gt   = blockIdx.x * blockDim.x + threadIdx.x;
  int wid  = gt >> 6;
  int lane = gt & 63;
  const float* src = (wid < B_ * L_) ? (s1 + (size_t)wid * F_)
                                     : (s2 + (size_t)(wid - B_ * L_) * F_);
  float2 v = ((const float2*)src)[lane];
  float s = v.x * v.x + v.y * v.y;
#pragma unroll
  for (int o = 32; o > 0; o >>= 1) s += __shfl_xor(s, o, 64);
  if (lane == 0) ws[OFF_N1 + wid] = s;
}

// cost matrix, skewed layout: C(c, r) at (c + 4*(r>>4))*1024 + r per batch.
__global__ __launch_bounds__(256) void cost_kernel(const float* __restrict__ s1,
                                                   const float* __restrict__ s2,
                                                   float* __restrict__ ws) {
  __shared__ short aL[128][136];
  __shared__ short bL[128][136];
  __shared__ float q1[128], q2[128];

  const int tid = threadIdx.x;
  const int b   = blockIdx.y;
  const int tc  = blockIdx.x & 7;
  const int tr  = blockIdx.x >> 3;

  const float* Ap = s1 + (size_t)b * L_ * F_ + (size_t)tr * 128 * F_;
  const float* Bp = s2 + (size_t)b * L_ * F_ + (size_t)tc * 128 * F_;

#pragma unroll 4
  for (int it = 0; it < 16; ++it) {
    int idx = it * 1024 + tid * 4;
    int r = idx >> 7, cc = idx & 127;
    float4 va = *(const float4*)(Ap + idx);
    float4 vb = *(const float4*)(Bp + idx);
    *(uint2*)&aL[r][cc] = make_uint2(pack2(va.x, va.y), pack2(va.z, va.w));
    *(uint2*)&bL[r][cc] = make_uint2(pack2(vb.x, vb.y), pack2(vb.z, vb.w));
  }
  if (tid < 128) q1[tid] = ws[OFF_N1 + (size_t)b * L_ + tr * 128 + tid];
  else           q2[tid - 128] = ws[OFF_N2 + (size_t)b * L_ + tc * 128 + (tid - 128)];
  __syncthreads();

  const int wave = tid >> 6, lane = tid & 63, quad = lane >> 4, l16 = lane & 15;
  const int m0 = (wave >> 1) * 64, n0 = (wave & 1) * 64;

  f32x4 acc[4][4] = {};
#pragma unroll
  for (int kc = 0; kc < 4; ++kc) {
    short8 af[4], bf[4];
#pragma unroll
    for (int mi = 0; mi < 4; ++mi)
      af[mi] = *(const short8*)&aL[m0 + mi * 16 + l16][kc * 32 + quad * 8];
#pragma unroll
    for (int nj = 0; nj < 4; ++nj)
      bf[nj] = *(const short8*)&bL[n0 + nj * 16 + l16][kc * 32 + quad * 8];
#pragma unroll
    for (int mi = 0; mi < 4; ++mi)
#pragma unroll
      for (int nj = 0; nj < 4; ++nj)
        acc[mi][nj] = __builtin_amdgcn_mfma_f32_16x16x32_bf16(af[mi], bf[nj], acc[mi][nj], 0, 0, 0);
  }

  float* Cb = ws + (size_t)b * SKEW_PB;
#pragma unroll
  for (int mi = 0; mi < 4; ++mi)
#pragma unroll
    for (int nj = 0; nj < 4; ++nj) {
      int lr0 = m0 + mi * 16 + quad * 4;
      int lc  = n0 + nj * 16 + l16;
      int r0  = tr * 128 + lr0;
      int c   = tc * 128 + lc;
      float4 v;
      v.x = sqrtf(fmaxf(q1[lr0 + 0] + q2[lc] - 2.0f * acc[mi][nj][0], 0.0f));
      v.y = sqrtf(fmaxf(q1[lr0 + 1] + q2[lc] - 2.0f * acc[mi][nj][1], 0.0f));
      v.z = sqrtf(fmaxf(q1[lr0 + 2] + q2[lc] - 2.0f * acc[mi][nj][2], 0.0f));
      v.w = sqrtf(fmaxf(q1[lr0 + 3] + q2[lc] - 2.0f * acc[mi][nj][3], 0.0f));
      *(float4*)&Cb[(size_t)(c + S_ * (r0 >> 4)) * 1024 + r0] = v;
    }
}

// One block per batch. Wave 0 computes DTW (lane l owns rows 16l..16l+15);
// waves 1..4 stage skewed rows global->LDS one 16-row segment ahead.
__global__ __launch_bounds__(320, 1) void dtw_kernel(const float* __restrict__ ws,
                                                     float* __restrict__ out) {
  __shared__ float colLds[32][1024];  // 128 KB: double-buffered 16-row segments

  const int b    = blockIdx.x;
  const int tid  = threadIdx.x;
  const int wave = tid >> 6;
  const int lane = tid & 63;
  const float* Cb = ws + (size_t)b * SKEW_PB;

  if (wave != 0) {
    // ---------------- loader waves ----------------
    const int rbase = (wave - 1) * 4;  // 4 rows per wave per segment
    auto loadSeg = [&](int g) {
#pragma unroll
      for (int i = 0; i < 4; ++i) {
        int u = g * 16 + rbase + i;
        const float4* src = (const float4*)(Cb + (size_t)u * 1024);
        float4* dst = (float4*)&colLds[u & 31][0];
#pragma unroll
        for (int q = 0; q < 4; ++q) dst[q * 64 + lane] = src[q * 64 + lane];
      }
    };
    loadSeg(0);
    for (int s = 0; s < NSEG_; ++s) {
      __syncthreads();                 // publish seg s; compute starts it
      if (s < NSEG_ - 1) loadSeg(s + 1);
    }
    return;
  }

  // ---------------- compute wave ----------------
  float left[16];
#pragma unroll
  for (int r = 0; r < 16; ++r) left[r] = BIGV;
  float bot = BIGV;
  float sh[4] = {BIGV, BIGV, BIGV, BIGV};
  float result = 0.0f;
  const bool l0 = (lane == 0);
  int col = -S_ * lane;  // column index at current step
  float4 pre[2][4];

  for (int s = 0; s < NSEG_; ++s) {
    __syncthreads();  // seg s ready in LDS half (s&1)
    {
      const float4* rp0 = (const float4*)&colLds[(16 * s) & 31][lane * 16];
      const float4* rp1 = (const float4*)&colLds[(16 * s + 1) & 31][lane * 16];
#pragma unroll
      for (int q = 0; q < 4; ++q) { pre[0][q] = rp0[q]; pre[1][q] = rp1[q]; }
    }
#pragma unroll
    for (int k = 0; k < 16; ++k) {
      const int t = 16 * s + k;
      float shN = __shfl_up(bot, 1, 64);

      const float4* cb = pre[k & 1];
      float cv[16] = { cb[0].x, cb[0].y, cb[0].z, cb[0].w,
                       cb[1].x, cb[1].y, cb[1].z, cb[1].w,
                       cb[2].x, cb[2].y, cb[2].z, cb[2].w,
                       cb[3].x, cb[3].y, cb[3].z, cb[3].w };

      if (k < 14) {  // depth-2 LDS prefetch (stays within seg s)
        const float4* rp = (const float4*)&colLds[(t + 2) & 31][lane * 16];
#pragma unroll
        for (int q = 0; q < 4; ++q) pre[k & 1][q] = rp[q];
      }

      // ring: slot written at t read as diag at t+4, as up at t+3
      float dgT = l0 ? ((t == 0) ? 0.0f : BIGV) : sh[k & 3];
      float upT = l0 ? BIGV : sh[(k + 1) & 3];
      bool act = ((unsigned)col < 1024u);
      float c0 = act ? cv[0] : BIGV;  // only head masked; induction keeps
                                      // inactive-lane state >= ~1e9
      float cur = c0 + fminf(fminf(dgT, upT), left[0]);
      float nl[16];
      nl[0] = cur;
#pragma unroll
      for (int r = 1; r < 16; ++r) {
        cur = cv[r] + fminf(fminf(left[r - 1], left[r]), cur);  // v_min3 + v_add
        nl[r] = cur;
      }
#pragma unroll
      for (int r = 0; r < 16; ++r) left[r] = nl[r];
      bot = nl[15];
      sh[k & 3] = shN;

      if (t == 1275) result = bot;  // lane 63 at c=1023: D[1024][1024]
      col += 1;
    }
  }
  if (lane == 63) out[b] = 1.0f / (1.0f + result * (1.0f / 2048.0f));
}

extern "C" void kernel_launch(void* const* d_in, const int* in_sizes, int n_in,
                              void* d_out, int out_size, void* d_ws, size_t ws_size,
                              hipStream_t stream) {
  const float* s1 = (const float*)d_in[0];
  const float* s2 = (const float*)d_in[1];
  float* out = (float*)d_out;
  float* ws  = (float*)d_ws;

  norm_kernel<<<dim3((2 * B_ * L_) / 4), 256, 0, stream>>>(s1, s2, ws);
  cost_kernel<<<dim3(64, B_), 256, 0, stream>>>(s1, s2, ws);
  dtw_kernel<<<dim3(B_), 320, 0, stream>>>(ws, out);
}